// Round 9
// baseline (212.190 us; speedup 1.0000x reference)
//
#include <hip/hip_runtime.h>
#include <hip/hip_bf16.h>

typedef __hip_bfloat16 bf16;
using bfv8 = __attribute__((ext_vector_type(8))) __bf16;
using f4_t = __attribute__((ext_vector_type(4))) float;

#define DEVI static __device__ __forceinline__

DEVI unsigned short f2bu(float f) {
    bf16 h = __float2bfloat16(f);
    return __builtin_bit_cast(unsigned short, h);
}
DEVI ushort4 f4_to_b4(float4 v) {
    ushort4 r;
    r.x = f2bu(v.x); r.y = f2bu(v.y); r.z = f2bu(v.z); r.w = f2bu(v.w);
    return r;
}
DEVI void gl2lds16(const void* g, void* l) {
    __builtin_amdgcn_global_load_lds((const __attribute__((address_space(1))) void*)g,
                                     (__attribute__((address_space(3))) void*)l, 16, 0, 0);
}

// DPP row_ror<N>: rotate within each 16-lane row (VALU only, no DS pipe).
template<int N>
DEVI float row_ror(float x) {
    return __builtin_bit_cast(float,
        __builtin_amdgcn_update_dpp(0, __builtin_bit_cast(int, x), 0x120 | N, 0xF, 0xF, false));
}
DEVI float max16(float x) {
    x = fmaxf(x, row_ror<8>(x));
    x = fmaxf(x, row_ror<4>(x));
    x = fmaxf(x, row_ror<2>(x));
    x = fmaxf(x, row_ror<1>(x));
    return x;
}
DEVI float sum16(float x) {
    x += row_ror<8>(x);
    x += row_ror<4>(x);
    x += row_ror<2>(x);
    x += row_ror<1>(x);
    return x;
}

// ---------------------------------------------------------------------------
// prep_all: grid-stride cast (blocks [0,2048), 4 units each) + table blocking
// (blocks [2048,2066)). Grid-stride cuts CP dispatch ramp vs 8210 blocks (G11).
// ---------------------------------------------------------------------------
__global__ __launch_bounds__(256) void prep_all(
    const float* __restrict__ x, const float* __restrict__ wq, const float* __restrict__ wk,
    const float* __restrict__ wv, const float* __restrict__ wo,
    const float* __restrict__ pek, const float* __restrict__ pev,
    bf16* __restrict__ xb, bf16* __restrict__ wqb, bf16* __restrict__ wkb,
    bf16* __restrict__ wvb, bf16* __restrict__ wob,
    bf16* __restrict__ pekBlk, bf16* __restrict__ pevBlk)
{
    __shared__ bf16 t[64][72];
    if (blockIdx.x < 2048) {
        const size_t X4 = 1u << 20, W4 = 1u << 18;
#pragma unroll
        for (int u = 0; u < 4; u++) {
            size_t i = (size_t)(blockIdx.x + 2048 * u) * 256 + threadIdx.x;   // float4 index
            const float* src; bf16* dst; size_t off;
            if (i < X4)              { src = x;  dst = xb;  off = i; }
            else if (i < X4 + W4)    { src = wq; dst = wqb; off = i - X4; }
            else if (i < X4 + 2*W4)  { src = wk; dst = wkb; off = i - X4 - W4; }
            else if (i < X4 + 3*W4)  { src = wv; dst = wvb; off = i - X4 - 2*W4; }
            else                     { src = wo; dst = wob; off = i - X4 - 3*W4; }
            float4 v = ((const float4*)src)[off];
            ((ushort4*)dst)[off] = f4_to_b4(v);
        }
        return;
    }
    const int b = blockIdx.x - 2048;          // 0..17
    const int r = threadIdx.x >> 2, c0 = (threadIdx.x & 3) * 16;

    if (b < 17) {
        const float* src = pek + (size_t)(64 * b + 1 + r) * 64 + c0;
        bf16* dst = pekBlk + (size_t)b * 4096 + r * 64 + c0;
#pragma unroll
        for (int j = 0; j < 16; j += 4)
            *(ushort4*)(dst + j) = f4_to_b4(*(const float4*)(src + j));
    }
    {   // pev: load rows, transpose through LDS
        const float* src = pev + (size_t)(64 * b + 1 + r) * 64 + c0;
#pragma unroll
        for (int j = 0; j < 16; j++) t[r][c0 + j] = __float2bfloat16(src[j]);
        __syncthreads();
        bf16* dst = pevBlk + (size_t)b * 4096 + r * 64 + c0;   // row d=r, cols j
#pragma unroll
        for (int j = 0; j < 16; j++) dst[j] = t[c0 + j][r];
    }
}

// ---------------------------------------------------------------------------
// NT GEMM v4 (unchanged from R4 — verified win): tile 128x128, BK=64, 4 waves
// 2x2 of 64x64 (acc[4][4]), XOR-swizzled LDS, width-16 global_load_lds.
//   mode 0, z<2 : bf16 out scattered to [B,H,L,HD] (Q,K)
//   mode 0, z==2: bf16 out to Vtb [BH][HD][L]
//   mode 1      : fp32 out row-major [M,1024]
// ---------------------------------------------------------------------------
__global__ __launch_bounds__(256, 2) void gemm_bt4(
    const bf16* __restrict__ A,
    const bf16* __restrict__ B0, const bf16* __restrict__ B1, const bf16* __restrict__ B2,
    bf16* __restrict__ outb, bf16* __restrict__ vtb, float* __restrict__ outf,
    int K, int mode)
{
    __shared__ __align__(16) bf16 smem[128 * 132];   // 33792 B
    bf16* As = smem;                  // 128 x 64
    bf16* Bs = smem + 128 * 64;       // 128 x 64
    bf16* Cb = smem;                  // epilogue bounce, stride 132

    const int tid  = threadIdx.x;
    const int lane = tid & 63, wave = tid >> 6;
    const int quad = lane >> 4, l16 = lane & 15;
    const int wm = wave >> 1, wn = wave & 1;
    const int m0 = blockIdx.y * 128, n0 = blockIdx.x * 128;
    const int z = blockIdx.z;
    const bf16* Bm = (z == 0) ? B0 : (z == 1) ? B1 : B2;

    const int srow8 = lane >> 3;            // 0..7
    const int scg   = (lane & 7) ^ srow8;   // XOR-swizzled source chunk
    const int x8    = l16 & 7;

    f4_t zero = {0.f, 0.f, 0.f, 0.f};
    f4_t acc[4][4];
#pragma unroll
    for (int i = 0; i < 4; i++)
#pragma unroll
        for (int j = 0; j < 4; j++) acc[i][j] = zero;

    const bf16* Ag = A  + (size_t)(m0 + 32 * wave + srow8) * K + scg * 8;
    const bf16* Bg = Bm + (size_t)(n0 + 32 * wave + srow8) * K + scg * 8;

    for (int k0 = 0; k0 < K; k0 += 64) {
#pragma unroll
        for (int i = 0; i < 4; i++) {
            gl2lds16(Ag + (size_t)(8 * i) * K + k0, &As[(32 * wave + 8 * i) * 64]);
            gl2lds16(Bg + (size_t)(8 * i) * K + k0, &Bs[(32 * wave + 8 * i) * 64]);
        }
        __syncthreads();
#pragma unroll
        for (int ks = 0; ks < 2; ks++) {
            bfv8 af[4], bfr[4];
#pragma unroll
            for (int mt = 0; mt < 4; mt++)
                af[mt] = *(const bfv8*)&As[(wm * 64 + mt * 16 + l16) * 64 + ((ks * 4 + quad) ^ x8) * 8];
#pragma unroll
            for (int nt = 0; nt < 4; nt++)
                bfr[nt] = *(const bfv8*)&Bs[(wn * 64 + nt * 16 + l16) * 64 + ((ks * 4 + quad) ^ x8) * 8];
#pragma unroll
            for (int mt = 0; mt < 4; mt++)
#pragma unroll
                for (int nt = 0; nt < 4; nt++)
                    acc[mt][nt] = __builtin_amdgcn_mfma_f32_16x16x32_bf16(af[mt], bfr[nt], acc[mt][nt], 0, 0, 0);
        }
        __syncthreads();
    }

    if (mode == 1) {       // fp32 row-major direct stores
#pragma unroll
        for (int mt = 0; mt < 4; mt++)
#pragma unroll
            for (int nt = 0; nt < 4; nt++)
#pragma unroll
                for (int r = 0; r < 4; r++) {
                    int m = m0 + wm * 64 + mt * 16 + quad * 4 + r;
                    int n = n0 + wn * 64 + nt * 16 + l16;
                    outf[(size_t)m * 1024 + n] = acc[mt][nt][r];
                }
        return;
    }

    const int b  = m0 >> 10, l0 = m0 & 1023, h0 = n0 >> 6;   // n0 covers heads h0, h0+1
    if (z < 2) {
        // bounce [m][n], stride 132
#pragma unroll
        for (int mt = 0; mt < 4; mt++)
#pragma unroll
            for (int nt = 0; nt < 4; nt++)
#pragma unroll
                for (int r = 0; r < 4; r++) {
                    int mm = wm * 64 + mt * 16 + quad * 4 + r;
                    int nn = wn * 64 + nt * 16 + l16;
                    Cb[mm * 132 + nn] = __float2bfloat16(acc[mt][nt][r]);
                }
        __syncthreads();
        bf16* ob = outb + (size_t)z * (4 * 16 * 1024 * 64);
        const int hp = tid >> 7, lrow = tid & 127;           // 2 heads x 128 l-rows
        bf16* dst = ob + ((size_t)((b * 16 + h0 + hp) * 1024) + l0 + lrow) * 64;
        const bf16* srcl = &Cb[lrow * 132 + hp * 64];
#pragma unroll
        for (int j = 0; j < 8; j++)
            *(int4*)(dst + 8 * j) = *(const int4*)(srcl + 8 * j);
    } else {
        // bounce transposed [n][m], stride 132 -> write V^T directly
#pragma unroll
        for (int mt = 0; mt < 4; mt++)
#pragma unroll
            for (int nt = 0; nt < 4; nt++)
#pragma unroll
                for (int r = 0; r < 4; r++) {
                    int mm = wm * 64 + mt * 16 + quad * 4 + r;
                    int nn = wn * 64 + nt * 16 + l16;
                    Cb[nn * 132 + mm] = __float2bfloat16(acc[mt][nt][r]);
                }
        __syncthreads();
        const int ri = tid >> 1, c0 = (tid & 1) * 64;        // ri = n' in [0,128)
        const int n = n0 + ri, h = n >> 6, hd = n & 63;
        bf16* dst = vtb + ((size_t)((b * 16 + h) * 64 + hd)) * 1024 + l0 + c0;
        const bf16* srcl = &Cb[ri * 132 + c0];
#pragma unroll
        for (int j = 0; j < 8; j++)
            *(int4*)(dst + 8 * j) = *(const int4*)(srcl + 8 * j);
    }
}

// ---------------------------------------------------------------------------
// attn_k v9 = R8 two-pass strip-merge + DIAGONAL-TILE FRAGMENT SKIP:
// on the diagonal K-tile (kt==g), wave w has valid columns only in fragments
// nt <= w. Skip the QK^T MFMAs, pek MFMAs and skew shuffles for nt >= ntV
// (= w+1; wave-uniform scalar branch) and set sc = -1e30 directly — softmax
// path untouched, zero numerical change. Saves ~37% of the S-phase on the
// 1024/8704 diagonal tiles.
// ---------------------------------------------------------------------------
__global__ __launch_bounds__(256, 2) void attn_k(
    const bf16* __restrict__ Qb, const bf16* __restrict__ Kb, const bf16* __restrict__ Vtb,
    const bf16* __restrict__ pekBlk, const bf16* __restrict__ pevBlk, bf16* __restrict__ Ob)
{
    constexpr int ST = 104;
    __shared__ __align__(16) bf16 Ks[64 * 64];
    __shared__ __align__(16) bf16 Vs[64 * 64];
    __shared__ __align__(16) bf16 pekR[2 * 4096];
    __shared__ __align__(16) bf16 pevR[3 * 4096];
    __shared__ __align__(16) bf16 sU[4][16 * ST];
    __shared__ __align__(16) bf16 sP[4][16 * 64];

    const int tid  = threadIdx.x;
    const int lane = tid & 63, wave = tid >> 6;
    const int quad = lane >> 4, l16 = lane & 15;
    const int bh = blockIdx.x;
    const int y  = blockIdx.y;                    // 0..7

    bf16* myU = sU[wave];
    bf16* myP = sP[wave];

    const int srow8 = lane >> 3;
    const int scg   = (lane & 7) ^ srow8;
    const int x8    = l16 & 7;

    // ---- zero U once (band positions pass- and tile-invariant)
    {
        int* p = (int*)myU;
#pragma unroll
        for (int i = 0; i < 13; i++) p[lane + 64 * i] = 0;
    }

    const bf16* Kbh = Kb  + (size_t)bh * 1024 * 64;
    const bf16* Vbh = Vtb + (size_t)bh * 64 * 1024;
    const int b = bh >> 4, h = bh & 15;

    for (int pass = 0; pass < 2; pass++) {
        const int g   = pass ? y : 15 - y;        // heavy strip first
        const int s   = 4 * g + wave;
        const int nkt = g + 1;
        const int B0  = 15 - g;                   // window base block at kt=0

        // ---- Q A-fragments, pre-scaled by 1/8
        bfv8 qf[2];
        {
            const bf16* qp = Qb + ((size_t)bh * 1024 + 16 * s + l16) * 64 + quad * 8;
            qf[0] = *(const bfv8*)qp;
            qf[1] = *(const bfv8*)(qp + 32);
#pragma unroll
            for (int j = 0; j < 8; j++) {
                qf[0][j] = (__bf16)((float)qf[0][j] * 0.125f);
                qf[1][j] = (__bf16)((float)qf[1][j] * 0.125f);
            }
        }

        f4_t zero = {0.f, 0.f, 0.f, 0.f};
        f4_t o_acc[4];
        float m_i[4], l_i[4];
#pragma unroll
        for (int i = 0; i < 4; i++) { o_acc[i] = zero; m_i[i] = -1e30f; l_i[i] = 0.f; }

        // ---- prologue staging (tile 0): K/V, pek blocks {B0,B0+1}, pev {B0..B0+2}
#pragma unroll
        for (int i = 0; i < 2; i++) {
            const int row = 8 * wave + 32 * i + srow8;
            gl2lds16(Kbh + (size_t)row * 64 + scg * 8, &Ks[(8 * wave + 32 * i) * 64]);
            gl2lds16(Vbh + (size_t)row * 1024 + scg * 8, &Vs[(8 * wave + 32 * i) * 64]);
        }
#pragma unroll
        for (int i2 = 0; i2 < 2; i2++) {
            const int slot = (B0 + i2) & 1;
#pragma unroll
            for (int i = 0; i < 2; i++) {
                const int row = 16 * wave + 8 * i + srow8;
                gl2lds16(pekBlk + (size_t)(B0 + i2) * 4096 + row * 64 + scg * 8,
                         &pekR[slot * 4096 + (16 * wave + 8 * i) * 64]);
            }
        }
#pragma unroll
        for (int i2 = 0; i2 < 3; i2++) {
            const int slot = (B0 + i2) % 3;
#pragma unroll
            for (int i = 0; i < 2; i++) {
                const int row = 16 * wave + 8 * i + srow8;
                gl2lds16(pevBlk + (size_t)(B0 + i2) * 4096 + row * 64 + scg * 8,
                         &pevR[slot * 4096 + (16 * wave + 8 * i) * 64]);
            }
        }
        __syncthreads();   // drain for tile-0 staging of this pass

        bfv8 stK[2], stV[2], stPk[2], stPv[2];

        for (int kt = 0; kt < nkt; kt++) {
            const int k0 = kt << 6;
            const int Bb = kt - g + 15;           // window base block, in [0,15]
            const int bm3 = Bb % 3;
            const bool pf = (kt + 1 < nkt);
            const int ntV = (kt == g) ? (wave + 1) : 4;   // valid-fragment count (wave-uniform)

            if (pf) {   // ---- issue reg loads for tile kt+1 (land during compute)
                const int k0n = (kt + 1) << 6;
                const int bNew = Bb + 2, cNew = Bb + 3;
#pragma unroll
                for (int i = 0; i < 2; i++) {
                    const int row = 8 * wave + 32 * i + srow8;
                    stK[i] = *(const bfv8*)(Kbh + (size_t)(k0n + row) * 64 + scg * 8);
                    stV[i] = *(const bfv8*)(Vbh + (size_t)row * 1024 + k0n + scg * 8);
                }
#pragma unroll
                for (int i = 0; i < 2; i++) {
                    const int row = 16 * wave + 8 * i + srow8;
                    stPk[i] = *(const bfv8*)(pekBlk + (size_t)bNew * 4096 + row * 64 + scg * 8);
                    stPv[i] = *(const bfv8*)(pevBlk + (size_t)cNew * 4096 + row * 64 + scg * 8);
                }
            }

            // ---- S1 = Qs K^T (ntV frags), T = Qs Pek^T (ntV+1 frags) — all LDS
            f4_t s1[4], tt[5];
#pragma unroll
            for (int i = 0; i < 4; i++) s1[i] = zero;
#pragma unroll
            for (int i = 0; i < 5; i++) tt[i] = zero;
#pragma unroll
            for (int ks = 0; ks < 2; ks++) {
#pragma unroll
                for (int nt = 0; nt < 4; nt++) if (nt < ntV) {
                    bfv8 kf = *(const bfv8*)&Ks[(nt * 16 + l16) * 64 + ((ks * 4 + quad) ^ x8) * 8];
                    s1[nt] = __builtin_amdgcn_mfma_f32_16x16x32_bf16(qf[ks], kf, s1[nt], 0, 0, 0);
                }
#pragma unroll
                for (int nt = 0; nt < 5; nt++) if (nt <= ntV) {
                    const int off  = 48 - 16 * wave + 16 * nt;
                    const int slot = (Bb + (off >> 6)) & 1;
                    bfv8 pfr = *(const bfv8*)&pekR[slot * 4096 + ((off & 63) + l16) * 64
                                                  + ((ks * 4 + quad) ^ x8) * 8];
                    tt[nt] = __builtin_amdgcn_mfma_f32_16x16x32_bf16(qf[ks], pfr, tt[nt], 0, 0, 0);
                }
            }

            // ---- skew gather: rotations + select (skipped frags -> -1e30); causal mask
            float sc[4][4];
#pragma unroll
            for (int r = 0; r < 4; r++) {
                int qq = quad * 4 + r;
                int t  = l16 + 15 - qq;
                int srcl = quad * 16 + (t & 15);
                bool lo = (t < 16);
                float rot[5];
#pragma unroll
                for (int j = 0; j < 5; j++) if (j <= ntV) rot[j] = __shfl(tt[j][r], srcl, 64);
#pragma unroll
                for (int nt = 0; nt < 4; nt++) {
                    if (nt < ntV) {
                        float s2 = lo ? rot[nt] : rot[nt + 1];
                        float v = s1[nt][r] + s2;
                        int kk = nt * 16 + l16;
                        if (k0 + kk > 16 * s + qq) v = -1e30f;
                        sc[nt][r] = v;
                    } else {
                        sc[nt][r] = -1e30f;
                    }
                }
            }

            // ---- online softmax (DPP reductions, VALU-only) — unchanged
            float alpha[4];
#pragma unroll
            for (int r = 0; r < 4; r++) {
                float mt = fmaxf(fmaxf(sc[0][r], sc[1][r]), fmaxf(sc[2][r], sc[3][r]));
                mt = max16(mt);
                float mnew = fmaxf(m_i[r], mt);
                alpha[r] = __expf(m_i[r] - mnew);
                m_i[r] = mnew;
            }
#pragma unroll
            for (int nt = 0; nt < 4; nt++)
#pragma unroll
                for (int r = 0; r < 4; r++)
                    sc[nt][r] = __expf(sc[nt][r] - m_i[r]);
#pragma unroll
            for (int r = 0; r < 4; r++) {
                float rs = sum16(sc[0][r] + sc[1][r] + sc[2][r] + sc[3][r]);
                l_i[r] = l_i[r] * alpha[r] + rs;
#pragma unroll
                for (int nt = 0; nt < 4; nt++) o_acc[nt][r] *= alpha[r];
            }

            // ---- scatter P (XOR-swizzled, stride 64) and banded U (all nt:
            // zeros must overwrite stale LDS for skipped fragments)
#pragma unroll
            for (int nt = 0; nt < 4; nt++)
#pragma unroll
                for (int r = 0; r < 4; r++) {
                    int qq = quad * 4 + r;
                    int kk = nt * 16 + l16;
                    bf16 pb = __float2bfloat16(sc[nt][r]);
                    myP[qq * 64 + (((kk >> 3) ^ (qq & 7)) << 3) + (kk & 7)] = pb;
                    myU[qq * ST + kk - qq + 15] = pb;
                }

            // ---- O += P V ; O += U Pev — all LDS
#pragma unroll
            for (int ks = 0; ks < 2; ks++) {
                bfv8 pa = *(const bfv8*)&myP[l16 * 64 + (((ks * 4 + quad) ^ x8) << 3)];
#pragma unroll
                for (int nt = 0; nt < 4; nt++) {
                    bfv8 vf = *(const bfv8*)&Vs[(nt * 16 + l16) * 64 + ((ks * 4 + quad) ^ x8) * 8];
                    o_acc[nt] = __builtin_amdgcn_mfma_f32_16x16x32_bf16(pa, vf, o_acc[nt], 0, 0, 0);
                }
            }
#pragma unroll
            for (int ks = 0; ks < 3; ks++) {
                bfv8 ua = *(const bfv8*)&myU[l16 * ST + ks * 32 + quad * 8];
                const int off2 = 48 - 16 * wave + 32 * ks + 8 * quad;
                int slot2 = bm3 + (off2 >> 6);
                if (slot2 >= 3) slot2 -= 3;
                const int chunk = (((off2 & 63) >> 3) ^ x8);
#pragma unroll
                for (int nt = 0; nt < 4; nt++) {
                    bfv8 pvf = *(const bfv8*)&pevR[slot2 * 4096 + (nt * 16 + l16) * 64 + chunk * 8];
                    o_acc[nt] = __builtin_amdgcn_mfma_f32_16x16x32_bf16(ua, pvf, o_acc[nt], 0, 0, 0);
                }
            }
            __syncthreads();   // all waves done reading this tile's LDS

            if (pf) {   // ---- write staged regs into LDS (same dests gl2lds used)
                const int Bn = Bb + 1;
                const int slotK = (Bn + 1) & 1, slotV = (Bn + 2) % 3;
#pragma unroll
                for (int i = 0; i < 2; i++) {
                    *(bfv8*)&Ks[(8 * wave + 32 * i) * 64 + lane * 8] = stK[i];
                    *(bfv8*)&Vs[(8 * wave + 32 * i) * 64 + lane * 8] = stV[i];
                }
#pragma unroll
                for (int i = 0; i < 2; i++) {
                    *(bfv8*)&pekR[slotK * 4096 + (16 * wave + 8 * i) * 64 + lane * 8] = stPk[i];
                    *(bfv8*)&pevR[slotV * 4096 + (16 * wave + 8 * i) * 64 + lane * 8] = stPv[i];
                }
            }
            __syncthreads();   // staged writes visible before next tile's compute
        }

        // ---- epilogue for this pass
#pragma unroll
        for (int nt = 0; nt < 4; nt++)
#pragma unroll
            for (int r = 0; r < 4; r++) {
                int q = 16 * s + quad * 4 + r;
                int d = nt * 16 + l16;
                Ob[((size_t)(b * 1024 + q)) * 1024 + h * 64 + d] = __float2bfloat16(o_acc[nt][r] / l_i[r]);
            }
    }
}

// ---------------------------------------------------------------------------
extern "C" void kernel_launch(void* const* d_in, const int* in_sizes, int n_in,
                              void* d_out, int out_size, void* d_ws, size_t ws_size,
                              hipStream_t stream) {
    const float* x   = (const float*)d_in[0];
    const float* Wq  = (const float*)d_in[1];
    const float* Wk  = (const float*)d_in[2];
    const float* Wv  = (const float*)d_in[3];
    const float* Wo  = (const float*)d_in[4];
    const float* pek = (const float*)d_in[5];
    const float* pev = (const float*)d_in[6];

    const size_t MB = 1u << 20;
    char* ws = (char*)d_ws;
    bf16* xb     = (bf16*)(ws + 0);          // 8 MB; dead after QKV gemm -> reused as Ao
    bf16* Wqb    = (bf16*)(ws + 8  * MB);
    bf16* Wkb    = (bf16*)(ws + 10 * MB);
    bf16* Wvb    = (bf16*)(ws + 12 * MB);
    bf16* Wob    = (bf16*)(ws + 14 * MB);
    bf16* Qb     = (bf16*)(ws + 16 * MB);    // Q,K contiguous (z-offset in epilogue)
    bf16* Kb     = (bf16*)(ws + 24 * MB);
    bf16* Vtb    = (bf16*)(ws + 32 * MB);    // V^T written directly by gemm z=2
    bf16* pekBlk = (bf16*)(ws + 48 * MB);            // 17*4096*2 B
    bf16* pevBlk = (bf16*)(ws + 48 * MB + 256*1024); // 18*4096*2 B
    bf16* Ao     = xb;

    prep_all<<<dim3(2066), 256, 0, stream>>>(x, Wq, Wk, Wv, Wo, pek, pev,
                                             xb, Wqb, Wkb, Wvb, Wob, pekBlk, pevBlk);
    gemm_bt4<<<dim3(8, 32, 3), 256, 0, stream>>>(xb, Wqb, Wkb, Wvb, Qb, Vtb, nullptr, 1024, 0);
    attn_k<<<dim3(64, 8), 256, 0, stream>>>(Qb, Kb, Vtb, pekBlk, pevBlk, Ao);
    gemm_bt4<<<dim3(8, 32, 1), 256, 0, stream>>>(Ao, Wob, nullptr, nullptr, nullptr, nullptr, (float*)d_out, 1024, 1);
}

// Round 10
// 208.558 us; speedup vs baseline: 1.0174x; 1.0174x over previous
//
#include <hip/hip_runtime.h>
#include <hip/hip_bf16.h>

typedef __hip_bfloat16 bf16;
using bfv8 = __attribute__((ext_vector_type(8))) __bf16;
using f4_t = __attribute__((ext_vector_type(4))) float;

#define DEVI static __device__ __forceinline__

DEVI unsigned short f2bu(float f) {
    bf16 h = __float2bfloat16(f);
    return __builtin_bit_cast(unsigned short, h);
}
DEVI ushort4 f4_to_b4(float4 v) {
    ushort4 r;
    r.x = f2bu(v.x); r.y = f2bu(v.y); r.z = f2bu(v.z); r.w = f2bu(v.w);
    return r;
}
DEVI void gl2lds16(const void* g, void* l) {
    __builtin_amdgcn_global_load_lds((const __attribute__((address_space(1))) void*)g,
                                     (__attribute__((address_space(3))) void*)l, 16, 0, 0);
}

// DPP row_ror<N>: rotate within each 16-lane row (VALU only, no DS pipe).
template<int N>
DEVI float row_ror(float x) {
    return __builtin_bit_cast(float,
        __builtin_amdgcn_update_dpp(0, __builtin_bit_cast(int, x), 0x120 | N, 0xF, 0xF, false));
}
DEVI float max16(float x) {
    x = fmaxf(x, row_ror<8>(x));
    x = fmaxf(x, row_ror<4>(x));
    x = fmaxf(x, row_ror<2>(x));
    x = fmaxf(x, row_ror<1>(x));
    return x;
}
DEVI float sum16(float x) {
    x += row_ror<8>(x);
    x += row_ror<4>(x);
    x += row_ror<2>(x);
    x += row_ror<1>(x);
    return x;
}

// ---------------------------------------------------------------------------
// prep_all: grid-stride cast (blocks [0,2048), 4 units each) + table blocking
// (blocks [2048,2066)).
// ---------------------------------------------------------------------------
__global__ __launch_bounds__(256) void prep_all(
    const float* __restrict__ x, const float* __restrict__ wq, const float* __restrict__ wk,
    const float* __restrict__ wv, const float* __restrict__ wo,
    const float* __restrict__ pek, const float* __restrict__ pev,
    bf16* __restrict__ xb, bf16* __restrict__ wqb, bf16* __restrict__ wkb,
    bf16* __restrict__ wvb, bf16* __restrict__ wob,
    bf16* __restrict__ pekBlk, bf16* __restrict__ pevBlk)
{
    __shared__ bf16 t[64][72];
    if (blockIdx.x < 2048) {
        const size_t X4 = 1u << 20, W4 = 1u << 18;
#pragma unroll
        for (int u = 0; u < 4; u++) {
            size_t i = (size_t)(blockIdx.x + 2048 * u) * 256 + threadIdx.x;   // float4 index
            const float* src; bf16* dst; size_t off;
            if (i < X4)              { src = x;  dst = xb;  off = i; }
            else if (i < X4 + W4)    { src = wq; dst = wqb; off = i - X4; }
            else if (i < X4 + 2*W4)  { src = wk; dst = wkb; off = i - X4 - W4; }
            else if (i < X4 + 3*W4)  { src = wv; dst = wvb; off = i - X4 - 2*W4; }
            else                     { src = wo; dst = wob; off = i - X4 - 3*W4; }
            float4 v = ((const float4*)src)[off];
            ((ushort4*)dst)[off] = f4_to_b4(v);
        }
        return;
    }
    const int b = blockIdx.x - 2048;          // 0..17
    const int r = threadIdx.x >> 2, c0 = (threadIdx.x & 3) * 16;

    if (b < 17) {
        const float* src = pek + (size_t)(64 * b + 1 + r) * 64 + c0;
        bf16* dst = pekBlk + (size_t)b * 4096 + r * 64 + c0;
#pragma unroll
        for (int j = 0; j < 16; j += 4)
            *(ushort4*)(dst + j) = f4_to_b4(*(const float4*)(src + j));
    }
    {   // pev: load rows, transpose through LDS
        const float* src = pev + (size_t)(64 * b + 1 + r) * 64 + c0;
#pragma unroll
        for (int j = 0; j < 16; j++) t[r][c0 + j] = __float2bfloat16(src[j]);
        __syncthreads();
        bf16* dst = pevBlk + (size_t)b * 4096 + r * 64 + c0;   // row d=r, cols j
#pragma unroll
        for (int j = 0; j < 16; j++) dst[j] = t[c0 + j][r];
    }
}

// ---------------------------------------------------------------------------
// NT GEMM v5 = bt4 structure with __launch_bounds__(256, 3).
// Grid for QKV is 768 = 256 CUs x 3 exactly: at 3 blocks/CU the whole grid
// is ONE zero-tail residency wave (at 2/CU it was 1.5 waves -> ~25% makespan
// tax), plus 50% more TLP against the per-K-step vmcnt drain. VGPR cap at
// 3 waves/SIMD is 170; the structurally-identical m97 kernel used 164.
// RISK CHECK next round: if gemm WRITE_SIZE balloons -> spilled -> revert.
//   mode 0, z<2 : bf16 out scattered to [B,H,L,HD] (Q,K)
//   mode 0, z==2: bf16 out to Vtb [BH][HD][L]
//   mode 1      : fp32 out row-major [M,1024]
// ---------------------------------------------------------------------------
__global__ __launch_bounds__(256, 3) void gemm_bt4(
    const bf16* __restrict__ A,
    const bf16* __restrict__ B0, const bf16* __restrict__ B1, const bf16* __restrict__ B2,
    bf16* __restrict__ outb, bf16* __restrict__ vtb, float* __restrict__ outf,
    int K, int mode)
{
    __shared__ __align__(16) bf16 smem[128 * 132];   // 33792 B
    bf16* As = smem;                  // 128 x 64
    bf16* Bs = smem + 128 * 64;       // 128 x 64
    bf16* Cb = smem;                  // epilogue bounce, stride 132

    const int tid  = threadIdx.x;
    const int lane = tid & 63, wave = tid >> 6;
    const int quad = lane >> 4, l16 = lane & 15;
    const int wm = wave >> 1, wn = wave & 1;
    const int m0 = blockIdx.y * 128, n0 = blockIdx.x * 128;
    const int z = blockIdx.z;
    const bf16* Bm = (z == 0) ? B0 : (z == 1) ? B1 : B2;

    const int srow8 = lane >> 3;            // 0..7
    const int scg   = (lane & 7) ^ srow8;   // XOR-swizzled source chunk
    const int x8    = l16 & 7;

    f4_t zero = {0.f, 0.f, 0.f, 0.f};
    f4_t acc[4][4];
#pragma unroll
    for (int i = 0; i < 4; i++)
#pragma unroll
        for (int j = 0; j < 4; j++) acc[i][j] = zero;

    const bf16* Ag = A  + (size_t)(m0 + 32 * wave + srow8) * K + scg * 8;
    const bf16* Bg = Bm + (size_t)(n0 + 32 * wave + srow8) * K + scg * 8;

    for (int k0 = 0; k0 < K; k0 += 64) {
#pragma unroll
        for (int i = 0; i < 4; i++) {
            gl2lds16(Ag + (size_t)(8 * i) * K + k0, &As[(32 * wave + 8 * i) * 64]);
            gl2lds16(Bg + (size_t)(8 * i) * K + k0, &Bs[(32 * wave + 8 * i) * 64]);
        }
        __syncthreads();
#pragma unroll
        for (int ks = 0; ks < 2; ks++) {
            bfv8 af[4], bfr[4];
#pragma unroll
            for (int mt = 0; mt < 4; mt++)
                af[mt] = *(const bfv8*)&As[(wm * 64 + mt * 16 + l16) * 64 + ((ks * 4 + quad) ^ x8) * 8];
#pragma unroll
            for (int nt = 0; nt < 4; nt++)
                bfr[nt] = *(const bfv8*)&Bs[(wn * 64 + nt * 16 + l16) * 64 + ((ks * 4 + quad) ^ x8) * 8];
#pragma unroll
            for (int mt = 0; mt < 4; mt++)
#pragma unroll
                for (int nt = 0; nt < 4; nt++)
                    acc[mt][nt] = __builtin_amdgcn_mfma_f32_16x16x32_bf16(af[mt], bfr[nt], acc[mt][nt], 0, 0, 0);
        }
        __syncthreads();
    }

    if (mode == 1) {       // fp32 row-major direct stores
#pragma unroll
        for (int mt = 0; mt < 4; mt++)
#pragma unroll
            for (int nt = 0; nt < 4; nt++)
#pragma unroll
                for (int r = 0; r < 4; r++) {
                    int m = m0 + wm * 64 + mt * 16 + quad * 4 + r;
                    int n = n0 + wn * 64 + nt * 16 + l16;
                    outf[(size_t)m * 1024 + n] = acc[mt][nt][r];
                }
        return;
    }

    const int b  = m0 >> 10, l0 = m0 & 1023, h0 = n0 >> 6;   // n0 covers heads h0, h0+1
    if (z < 2) {
        // bounce [m][n], stride 132
#pragma unroll
        for (int mt = 0; mt < 4; mt++)
#pragma unroll
            for (int nt = 0; nt < 4; nt++)
#pragma unroll
                for (int r = 0; r < 4; r++) {
                    int mm = wm * 64 + mt * 16 + quad * 4 + r;
                    int nn = wn * 64 + nt * 16 + l16;
                    Cb[mm * 132 + nn] = __float2bfloat16(acc[mt][nt][r]);
                }
        __syncthreads();
        bf16* ob = outb + (size_t)z * (4 * 16 * 1024 * 64);
        const int hp = tid >> 7, lrow = tid & 127;           // 2 heads x 128 l-rows
        bf16* dst = ob + ((size_t)((b * 16 + h0 + hp) * 1024) + l0 + lrow) * 64;
        const bf16* srcl = &Cb[lrow * 132 + hp * 64];
#pragma unroll
        for (int j = 0; j < 8; j++)
            *(int4*)(dst + 8 * j) = *(const int4*)(srcl + 8 * j);
    } else {
        // bounce transposed [n][m], stride 132 -> write V^T directly
#pragma unroll
        for (int mt = 0; mt < 4; mt++)
#pragma unroll
            for (int nt = 0; nt < 4; nt++)
#pragma unroll
                for (int r = 0; r < 4; r++) {
                    int mm = wm * 64 + mt * 16 + quad * 4 + r;
                    int nn = wn * 64 + nt * 16 + l16;
                    Cb[nn * 132 + mm] = __float2bfloat16(acc[mt][nt][r]);
                }
        __syncthreads();
        const int ri = tid >> 1, c0 = (tid & 1) * 64;        // ri = n' in [0,128)
        const int n = n0 + ri, h = n >> 6, hd = n & 63;
        bf16* dst = vtb + ((size_t)((b * 16 + h) * 64 + hd)) * 1024 + l0 + c0;
        const bf16* srcl = &Cb[ri * 132 + c0];
#pragma unroll
        for (int j = 0; j < 8; j++)
            *(int4*)(dst + 8 * j) = *(const int4*)(srcl + 8 * j);
    }
}

// ---------------------------------------------------------------------------
// attn_k v10 = exact R8 (two-pass strip-merge, no diagonal skip — R9 proved
// the wave-uniform fragment skip costs more in branch/reg overhead than it
// saves). Best measured warm time: 75.1-75.5 us.
// ---------------------------------------------------------------------------
__global__ __launch_bounds__(256, 2) void attn_k(
    const bf16* __restrict__ Qb, const bf16* __restrict__ Kb, const bf16* __restrict__ Vtb,
    const bf16* __restrict__ pekBlk, const bf16* __restrict__ pevBlk, bf16* __restrict__ Ob)
{
    constexpr int ST = 104;
    __shared__ __align__(16) bf16 Ks[64 * 64];
    __shared__ __align__(16) bf16 Vs[64 * 64];
    __shared__ __align__(16) bf16 pekR[2 * 4096];
    __shared__ __align__(16) bf16 pevR[3 * 4096];
    __shared__ __align__(16) bf16 sU[4][16 * ST];
    __shared__ __align__(16) bf16 sP[4][16 * 64];

    const int tid  = threadIdx.x;
    const int lane = tid & 63, wave = tid >> 6;
    const int quad = lane >> 4, l16 = lane & 15;
    const int bh = blockIdx.x;
    const int y  = blockIdx.y;                    // 0..7

    bf16* myU = sU[wave];
    bf16* myP = sP[wave];

    const int srow8 = lane >> 3;
    const int scg   = (lane & 7) ^ srow8;
    const int x8    = l16 & 7;

    // ---- zero U once (band positions pass- and tile-invariant)
    {
        int* p = (int*)myU;
#pragma unroll
        for (int i = 0; i < 13; i++) p[lane + 64 * i] = 0;
    }

    const bf16* Kbh = Kb  + (size_t)bh * 1024 * 64;
    const bf16* Vbh = Vtb + (size_t)bh * 64 * 1024;
    const int b = bh >> 4, h = bh & 15;

    for (int pass = 0; pass < 2; pass++) {
        const int g   = pass ? y : 15 - y;        // heavy strip first
        const int s   = 4 * g + wave;
        const int nkt = g + 1;
        const int B0  = 15 - g;                   // window base block at kt=0

        // ---- Q A-fragments, pre-scaled by 1/8
        bfv8 qf[2];
        {
            const bf16* qp = Qb + ((size_t)bh * 1024 + 16 * s + l16) * 64 + quad * 8;
            qf[0] = *(const bfv8*)qp;
            qf[1] = *(const bfv8*)(qp + 32);
#pragma unroll
            for (int j = 0; j < 8; j++) {
                qf[0][j] = (__bf16)((float)qf[0][j] * 0.125f);
                qf[1][j] = (__bf16)((float)qf[1][j] * 0.125f);
            }
        }

        f4_t zero = {0.f, 0.f, 0.f, 0.f};
        f4_t o_acc[4];
        float m_i[4], l_i[4];
#pragma unroll
        for (int i = 0; i < 4; i++) { o_acc[i] = zero; m_i[i] = -1e30f; l_i[i] = 0.f; }

        // ---- prologue staging (tile 0): K/V, pek blocks {B0,B0+1}, pev {B0..B0+2}
#pragma unroll
        for (int i = 0; i < 2; i++) {
            const int row = 8 * wave + 32 * i + srow8;
            gl2lds16(Kbh + (size_t)row * 64 + scg * 8, &Ks[(8 * wave + 32 * i) * 64]);
            gl2lds16(Vbh + (size_t)row * 1024 + scg * 8, &Vs[(8 * wave + 32 * i) * 64]);
        }
#pragma unroll
        for (int i2 = 0; i2 < 2; i2++) {
            const int slot = (B0 + i2) & 1;
#pragma unroll
            for (int i = 0; i < 2; i++) {
                const int row = 16 * wave + 8 * i + srow8;
                gl2lds16(pekBlk + (size_t)(B0 + i2) * 4096 + row * 64 + scg * 8,
                         &pekR[slot * 4096 + (16 * wave + 8 * i) * 64]);
            }
        }
#pragma unroll
        for (int i2 = 0; i2 < 3; i2++) {
            const int slot = (B0 + i2) % 3;
#pragma unroll
            for (int i = 0; i < 2; i++) {
                const int row = 16 * wave + 8 * i + srow8;
                gl2lds16(pevBlk + (size_t)(B0 + i2) * 4096 + row * 64 + scg * 8,
                         &pevR[slot * 4096 + (16 * wave + 8 * i) * 64]);
            }
        }
        __syncthreads();   // drain for tile-0 staging of this pass

        bfv8 stK[2], stV[2], stPk[2], stPv[2];

        for (int kt = 0; kt < nkt; kt++) {
            const int k0 = kt << 6;
            const int Bb = kt - g + 15;           // window base block, in [0,15]
            const int bm3 = Bb % 3;
            const bool pf = (kt + 1 < nkt);

            if (pf) {   // ---- issue reg loads for tile kt+1 (land during compute)
                const int k0n = (kt + 1) << 6;
                const int bNew = Bb + 2, cNew = Bb + 3;
#pragma unroll
                for (int i = 0; i < 2; i++) {
                    const int row = 8 * wave + 32 * i + srow8;
                    stK[i] = *(const bfv8*)(Kbh + (size_t)(k0n + row) * 64 + scg * 8);
                    stV[i] = *(const bfv8*)(Vbh + (size_t)row * 1024 + k0n + scg * 8);
                }
#pragma unroll
                for (int i = 0; i < 2; i++) {
                    const int row = 16 * wave + 8 * i + srow8;
                    stPk[i] = *(const bfv8*)(pekBlk + (size_t)bNew * 4096 + row * 64 + scg * 8);
                    stPv[i] = *(const bfv8*)(pevBlk + (size_t)cNew * 4096 + row * 64 + scg * 8);
                }
            }

            // ---- S1 = Qs K^T (4 frags), T = Qs Pek^T (5 frags) — all LDS
            f4_t s1[4], tt[5];
#pragma unroll
            for (int i = 0; i < 4; i++) s1[i] = zero;
#pragma unroll
            for (int i = 0; i < 5; i++) tt[i] = zero;
#pragma unroll
            for (int ks = 0; ks < 2; ks++) {
#pragma unroll
                for (int nt = 0; nt < 4; nt++) {
                    bfv8 kf = *(const bfv8*)&Ks[(nt * 16 + l16) * 64 + ((ks * 4 + quad) ^ x8) * 8];
                    s1[nt] = __builtin_amdgcn_mfma_f32_16x16x32_bf16(qf[ks], kf, s1[nt], 0, 0, 0);
                }
#pragma unroll
                for (int nt = 0; nt < 5; nt++) {
                    const int off  = 48 - 16 * wave + 16 * nt;
                    const int slot = (Bb + (off >> 6)) & 1;
                    bfv8 pfr = *(const bfv8*)&pekR[slot * 4096 + ((off & 63) + l16) * 64
                                                  + ((ks * 4 + quad) ^ x8) * 8];
                    tt[nt] = __builtin_amdgcn_mfma_f32_16x16x32_bf16(qf[ks], pfr, tt[nt], 0, 0, 0);
                }
            }

            // ---- skew gather: 5 rotations per row + select; causal mask
            float sc[4][4];
#pragma unroll
            for (int r = 0; r < 4; r++) {
                int qq = quad * 4 + r;
                int t  = l16 + 15 - qq;
                int srcl = quad * 16 + (t & 15);
                bool lo = (t < 16);
                float rot[5];
#pragma unroll
                for (int j = 0; j < 5; j++) rot[j] = __shfl(tt[j][r], srcl, 64);
#pragma unroll
                for (int nt = 0; nt < 4; nt++) {
                    float s2 = lo ? rot[nt] : rot[nt + 1];
                    float v = s1[nt][r] + s2;
                    int kk = nt * 16 + l16;
                    if (k0 + kk > 16 * s + qq) v = -1e30f;
                    sc[nt][r] = v;
                }
            }

            // ---- online softmax (DPP reductions, VALU-only)
            float alpha[4];
#pragma unroll
            for (int r = 0; r < 4; r++) {
                float mt = fmaxf(fmaxf(sc[0][r], sc[1][r]), fmaxf(sc[2][r], sc[3][r]));
                mt = max16(mt);
                float mnew = fmaxf(m_i[r], mt);
                alpha[r] = __expf(m_i[r] - mnew);
                m_i[r] = mnew;
            }
#pragma unroll
            for (int nt = 0; nt < 4; nt++)
#pragma unroll
                for (int r = 0; r < 4; r++)
                    sc[nt][r] = __expf(sc[nt][r] - m_i[r]);
#pragma unroll
            for (int r = 0; r < 4; r++) {
                float rs = sum16(sc[0][r] + sc[1][r] + sc[2][r] + sc[3][r]);
                l_i[r] = l_i[r] * alpha[r] + rs;
#pragma unroll
                for (int nt = 0; nt < 4; nt++) o_acc[nt][r] *= alpha[r];
            }

            // ---- scatter P (XOR-swizzled, stride 64) and banded U
#pragma unroll
            for (int nt = 0; nt < 4; nt++)
#pragma unroll
                for (int r = 0; r < 4; r++) {
                    int qq = quad * 4 + r;
                    int kk = nt * 16 + l16;
                    bf16 pb = __float2bfloat16(sc[nt][r]);
                    myP[qq * 64 + (((kk >> 3) ^ (qq & 7)) << 3) + (kk & 7)] = pb;
                    myU[qq * ST + kk - qq + 15] = pb;
                }

            // ---- O += P V ; O += U Pev — all LDS
#pragma unroll
            for (int ks = 0; ks < 2; ks++) {
                bfv8 pa = *(const bfv8*)&myP[l16 * 64 + (((ks * 4 + quad) ^ x8) << 3)];
#pragma unroll
                for (int nt = 0; nt < 4; nt++) {
                    bfv8 vf = *(const bfv8*)&Vs[(nt * 16 + l16) * 64 + ((ks * 4 + quad) ^ x8) * 8];
                    o_acc[nt] = __builtin_amdgcn_mfma_f32_16x16x32_bf16(pa, vf, o_acc[nt], 0, 0, 0);
                }
            }
#pragma unroll
            for (int ks = 0; ks < 3; ks++) {
                bfv8 ua = *(const bfv8*)&myU[l16 * ST + ks * 32 + quad * 8];
                const int off2 = 48 - 16 * wave + 32 * ks + 8 * quad;
                int slot2 = bm3 + (off2 >> 6);
                if (slot2 >= 3) slot2 -= 3;
                const int chunk = (((off2 & 63) >> 3) ^ x8);
#pragma unroll
                for (int nt = 0; nt < 4; nt++) {
                    bfv8 pvf = *(const bfv8*)&pevR[slot2 * 4096 + (nt * 16 + l16) * 64 + chunk * 8];
                    o_acc[nt] = __builtin_amdgcn_mfma_f32_16x16x32_bf16(ua, pvf, o_acc[nt], 0, 0, 0);
                }
            }
            __syncthreads();   // all waves done reading this tile's LDS

            if (pf) {   // ---- write staged regs into LDS (same dests gl2lds used)
                const int Bn = Bb + 1;
                const int slotK = (Bn + 1) & 1, slotV = (Bn + 2) % 3;
#pragma unroll
                for (int i = 0; i < 2; i++) {
                    *(bfv8*)&Ks[(8 * wave + 32 * i) * 64 + lane * 8] = stK[i];
                    *(bfv8*)&Vs[(8 * wave + 32 * i) * 64 + lane * 8] = stV[i];
                }
#pragma unroll
                for (int i = 0; i < 2; i++) {
                    *(bfv8*)&pekR[slotK * 4096 + (16 * wave + 8 * i) * 64 + lane * 8] = stPk[i];
                    *(bfv8*)&pevR[slotV * 4096 + (16 * wave + 8 * i) * 64 + lane * 8] = stPv[i];
                }
            }
            __syncthreads();   // staged writes visible before next tile's compute
        }

        // ---- epilogue for this pass
#pragma unroll
        for (int nt = 0; nt < 4; nt++)
#pragma unroll
            for (int r = 0; r < 4; r++) {
                int q = 16 * s + quad * 4 + r;
                int d = nt * 16 + l16;
                Ob[((size_t)(b * 1024 + q)) * 1024 + h * 64 + d] = __float2bfloat16(o_acc[nt][r] / l_i[r]);
            }
    }
}

// ---------------------------------------------------------------------------
extern "C" void kernel_launch(void* const* d_in, const int* in_sizes, int n_in,
                              void* d_out, int out_size, void* d_ws, size_t ws_size,
                              hipStream_t stream) {
    const float* x   = (const float*)d_in[0];
    const float* Wq  = (const float*)d_in[1];
    const float* Wk  = (const float*)d_in[2];
    const float* Wv  = (const float*)d_in[3];
    const float* Wo  = (const float*)d_in[4];
    const float* pek = (const float*)d_in[5];
    const float* pev = (const float*)d_in[6];

    const size_t MB = 1u << 20;
    char* ws = (char*)d_ws;
    bf16* xb     = (bf16*)(ws + 0);          // 8 MB; dead after QKV gemm -> reused as Ao
    bf16* Wqb    = (bf16*)(ws + 8  * MB);
    bf16* Wkb    = (bf16*)(ws + 10 * MB);
    bf16* Wvb    = (bf16*)(ws + 12 * MB);
    bf16* Wob    = (bf16*)(ws + 14 * MB);
    bf16* Qb     = (bf16*)(ws + 16 * MB);    // Q,K contiguous (z-offset in epilogue)
    bf16* Kb     = (bf16*)(ws + 24 * MB);
    bf16* Vtb    = (bf16*)(ws + 32 * MB);    // V^T written directly by gemm z=2
    bf16* pekBlk = (bf16*)(ws + 48 * MB);            // 17*4096*2 B
    bf16* pevBlk = (bf16*)(ws + 48 * MB + 256*1024); // 18*4096*2 B
    bf16* Ao     = xb;

    prep_all<<<dim3(2066), 256, 0, stream>>>(x, Wq, Wk, Wv, Wo, pek, pev,
                                             xb, Wqb, Wkb, Wvb, Wob, pekBlk, pevBlk);
    gemm_bt4<<<dim3(8, 32, 3), 256, 0, stream>>>(xb, Wqb, Wkb, Wvb, Qb, Vtb, nullptr, 1024, 0);
    attn_k<<<dim3(64, 8), 256, 0, stream>>>(Qb, Kb, Vtb, pekBlk, pevBlk, Ao);
    gemm_bt4<<<dim3(8, 32, 1), 256, 0, stream>>>(Ao, Wob, nullptr, nullptr, nullptr, nullptr, (float*)d_out, 1024, 1);
}

// Round 11
// 203.158 us; speedup vs baseline: 1.0445x; 1.0266x over previous
//
#include <hip/hip_runtime.h>
#include <hip/hip_bf16.h>

typedef __hip_bfloat16 bf16;
using bfv8 = __attribute__((ext_vector_type(8))) __bf16;
using f4_t = __attribute__((ext_vector_type(4))) float;

#define DEVI static __device__ __forceinline__

DEVI unsigned short f2bu(float f) {
    bf16 h = __float2bfloat16(f);
    return __builtin_bit_cast(unsigned short, h);
}
DEVI ushort4 f4_to_b4(float4 v) {
    ushort4 r;
    r.x = f2bu(v.x); r.y = f2bu(v.y); r.z = f2bu(v.z); r.w = f2bu(v.w);
    return r;
}
DEVI void gl2lds16(const void* g, void* l) {
    __builtin_amdgcn_global_load_lds((const __attribute__((address_space(1))) void*)g,
                                     (__attribute__((address_space(3))) void*)l, 16, 0, 0);
}

// DPP row_ror<N>: rotate within each 16-lane row (VALU only, no DS pipe).
template<int N>
DEVI float row_ror(float x) {
    return __builtin_bit_cast(float,
        __builtin_amdgcn_update_dpp(0, __builtin_bit_cast(int, x), 0x120 | N, 0xF, 0xF, false));
}
DEVI float max16(float x) {
    x = fmaxf(x, row_ror<8>(x));
    x = fmaxf(x, row_ror<4>(x));
    x = fmaxf(x, row_ror<2>(x));
    x = fmaxf(x, row_ror<1>(x));
    return x;
}
DEVI float sum16(float x) {
    x += row_ror<8>(x);
    x += row_ror<4>(x);
    x += row_ror<2>(x);
    x += row_ror<1>(x);
    return x;
}

// ---------------------------------------------------------------------------
// prep_all: grid-stride cast (blocks [0,2048), 4 units each) + table blocking
// (blocks [2048,2066)).
// ---------------------------------------------------------------------------
__global__ __launch_bounds__(256) void prep_all(
    const float* __restrict__ x, const float* __restrict__ wq, const float* __restrict__ wk,
    const float* __restrict__ wv, const float* __restrict__ wo,
    const float* __restrict__ pek, const float* __restrict__ pev,
    bf16* __restrict__ xb, bf16* __restrict__ wqb, bf16* __restrict__ wkb,
    bf16* __restrict__ wvb, bf16* __restrict__ wob,
    bf16* __restrict__ pekBlk, bf16* __restrict__ pevBlk)
{
    __shared__ bf16 t[64][72];
    if (blockIdx.x < 2048) {
        const size_t X4 = 1u << 20, W4 = 1u << 18;
#pragma unroll
        for (int u = 0; u < 4; u++) {
            size_t i = (size_t)(blockIdx.x + 2048 * u) * 256 + threadIdx.x;   // float4 index
            const float* src; bf16* dst; size_t off;
            if (i < X4)              { src = x;  dst = xb;  off = i; }
            else if (i < X4 + W4)    { src = wq; dst = wqb; off = i - X4; }
            else if (i < X4 + 2*W4)  { src = wk; dst = wkb; off = i - X4 - W4; }
            else if (i < X4 + 3*W4)  { src = wv; dst = wvb; off = i - X4 - 2*W4; }
            else                     { src = wo; dst = wob; off = i - X4 - 3*W4; }
            float4 v = ((const float4*)src)[off];
            ((ushort4*)dst)[off] = f4_to_b4(v);
        }
        return;
    }
    const int b = blockIdx.x - 2048;          // 0..17
    const int r = threadIdx.x >> 2, c0 = (threadIdx.x & 3) * 16;

    if (b < 17) {
        const float* src = pek + (size_t)(64 * b + 1 + r) * 64 + c0;
        bf16* dst = pekBlk + (size_t)b * 4096 + r * 64 + c0;
#pragma unroll
        for (int j = 0; j < 16; j += 4)
            *(ushort4*)(dst + j) = f4_to_b4(*(const float4*)(src + j));
    }
    {   // pev: load rows, transpose through LDS
        const float* src = pev + (size_t)(64 * b + 1 + r) * 64 + c0;
#pragma unroll
        for (int j = 0; j < 16; j++) t[r][c0 + j] = __float2bfloat16(src[j]);
        __syncthreads();
        bf16* dst = pevBlk + (size_t)b * 4096 + r * 64 + c0;   // row d=r, cols j
#pragma unroll
        for (int j = 0; j < 16; j++) dst[j] = t[c0 + j][r];
    }
}

// ---------------------------------------------------------------------------
// NT GEMM v4 (R4 config restored — (256,2); R10's (256,3) was null):
// tile 128x128, BK=64, 4 waves 2x2 of 64x64 (acc[4][4]), XOR-swizzled LDS,
// width-16 global_load_lds.
//   mode 0, z<2 : bf16 out scattered to [B,H,L,HD] (Q,K)
//   mode 0, z==2: bf16 out to Vtb [BH][HD][L]
//   mode 1      : fp32 out row-major [M,1024]
// ---------------------------------------------------------------------------
__global__ __launch_bounds__(256, 2) void gemm_bt4(
    const bf16* __restrict__ A,
    const bf16* __restrict__ B0, const bf16* __restrict__ B1, const bf16* __restrict__ B2,
    bf16* __restrict__ outb, bf16* __restrict__ vtb, float* __restrict__ outf,
    int K, int mode)
{
    __shared__ __align__(16) bf16 smem[128 * 132];   // 33792 B
    bf16* As = smem;                  // 128 x 64
    bf16* Bs = smem + 128 * 64;       // 128 x 64
    bf16* Cb = smem;                  // epilogue bounce, stride 132

    const int tid  = threadIdx.x;
    const int lane = tid & 63, wave = tid >> 6;
    const int quad = lane >> 4, l16 = lane & 15;
    const int wm = wave >> 1, wn = wave & 1;
    const int m0 = blockIdx.y * 128, n0 = blockIdx.x * 128;
    const int z = blockIdx.z;
    const bf16* Bm = (z == 0) ? B0 : (z == 1) ? B1 : B2;

    const int srow8 = lane >> 3;            // 0..7
    const int scg   = (lane & 7) ^ srow8;   // XOR-swizzled source chunk
    const int x8    = l16 & 7;

    f4_t zero = {0.f, 0.f, 0.f, 0.f};
    f4_t acc[4][4];
#pragma unroll
    for (int i = 0; i < 4; i++)
#pragma unroll
        for (int j = 0; j < 4; j++) acc[i][j] = zero;

    const bf16* Ag = A  + (size_t)(m0 + 32 * wave + srow8) * K + scg * 8;
    const bf16* Bg = Bm + (size_t)(n0 + 32 * wave + srow8) * K + scg * 8;

    for (int k0 = 0; k0 < K; k0 += 64) {
#pragma unroll
        for (int i = 0; i < 4; i++) {
            gl2lds16(Ag + (size_t)(8 * i) * K + k0, &As[(32 * wave + 8 * i) * 64]);
            gl2lds16(Bg + (size_t)(8 * i) * K + k0, &Bs[(32 * wave + 8 * i) * 64]);
        }
        __syncthreads();
#pragma unroll
        for (int ks = 0; ks < 2; ks++) {
            bfv8 af[4], bfr[4];
#pragma unroll
            for (int mt = 0; mt < 4; mt++)
                af[mt] = *(const bfv8*)&As[(wm * 64 + mt * 16 + l16) * 64 + ((ks * 4 + quad) ^ x8) * 8];
#pragma unroll
            for (int nt = 0; nt < 4; nt++)
                bfr[nt] = *(const bfv8*)&Bs[(wn * 64 + nt * 16 + l16) * 64 + ((ks * 4 + quad) ^ x8) * 8];
#pragma unroll
            for (int mt = 0; mt < 4; mt++)
#pragma unroll
                for (int nt = 0; nt < 4; nt++)
                    acc[mt][nt] = __builtin_amdgcn_mfma_f32_16x16x32_bf16(af[mt], bfr[nt], acc[mt][nt], 0, 0, 0);
        }
        __syncthreads();
    }

    if (mode == 1) {       // fp32 row-major direct stores
#pragma unroll
        for (int mt = 0; mt < 4; mt++)
#pragma unroll
            for (int nt = 0; nt < 4; nt++)
#pragma unroll
                for (int r = 0; r < 4; r++) {
                    int m = m0 + wm * 64 + mt * 16 + quad * 4 + r;
                    int n = n0 + wn * 64 + nt * 16 + l16;
                    outf[(size_t)m * 1024 + n] = acc[mt][nt][r];
                }
        return;
    }

    const int b  = m0 >> 10, l0 = m0 & 1023, h0 = n0 >> 6;   // n0 covers heads h0, h0+1
    if (z < 2) {
        // bounce [m][n], stride 132
#pragma unroll
        for (int mt = 0; mt < 4; mt++)
#pragma unroll
            for (int nt = 0; nt < 4; nt++)
#pragma unroll
                for (int r = 0; r < 4; r++) {
                    int mm = wm * 64 + mt * 16 + quad * 4 + r;
                    int nn = wn * 64 + nt * 16 + l16;
                    Cb[mm * 132 + nn] = __float2bfloat16(acc[mt][nt][r]);
                }
        __syncthreads();
        bf16* ob = outb + (size_t)z * (4 * 16 * 1024 * 64);
        const int hp = tid >> 7, lrow = tid & 127;           // 2 heads x 128 l-rows
        bf16* dst = ob + ((size_t)((b * 16 + h0 + hp) * 1024) + l0 + lrow) * 64;
        const bf16* srcl = &Cb[lrow * 132 + hp * 64];
#pragma unroll
        for (int j = 0; j < 8; j++)
            *(int4*)(dst + 8 * j) = *(const int4*)(srcl + 8 * j);
    } else {
        // bounce transposed [n][m], stride 132 -> write V^T directly
#pragma unroll
        for (int mt = 0; mt < 4; mt++)
#pragma unroll
            for (int nt = 0; nt < 4; nt++)
#pragma unroll
                for (int r = 0; r < 4; r++) {
                    int mm = wm * 64 + mt * 16 + quad * 4 + r;
                    int nn = wn * 64 + nt * 16 + l16;
                    Cb[nn * 132 + mm] = __float2bfloat16(acc[mt][nt][r]);
                }
        __syncthreads();
        const int ri = tid >> 1, c0 = (tid & 1) * 64;        // ri = n' in [0,128)
        const int n = n0 + ri, h = n >> 6, hd = n & 63;
        bf16* dst = vtb + ((size_t)((b * 16 + h) * 64 + hd)) * 1024 + l0 + c0;
        const bf16* srcl = &Cb[ri * 132 + c0];
#pragma unroll
        for (int j = 0; j < 8; j++)
            *(int4*)(dst + 8 * j) = *(const int4*)(srcl + 8 * j);
    }
}

// ---------------------------------------------------------------------------
// attn_k v11 = R8 two-pass strip-merge + T13 defer-max (THR=8):
// skip the m-update, alpha exps and 20 rescale muls when the whole wave's
// tile-max is within 8 of the running max — P then bounded by e^8, which
// bf16 stores at unchanged relative error; l_i normalizes scale out.
// First tile always takes the update path (m = -1e30). Wave-uniform branch
// via __all (s_cbranch on ballot, no divergence).
// ---------------------------------------------------------------------------
__global__ __launch_bounds__(256, 2) void attn_k(
    const bf16* __restrict__ Qb, const bf16* __restrict__ Kb, const bf16* __restrict__ Vtb,
    const bf16* __restrict__ pekBlk, const bf16* __restrict__ pevBlk, bf16* __restrict__ Ob)
{
    constexpr int ST = 104;
    __shared__ __align__(16) bf16 Ks[64 * 64];
    __shared__ __align__(16) bf16 Vs[64 * 64];
    __shared__ __align__(16) bf16 pekR[2 * 4096];
    __shared__ __align__(16) bf16 pevR[3 * 4096];
    __shared__ __align__(16) bf16 sU[4][16 * ST];
    __shared__ __align__(16) bf16 sP[4][16 * 64];

    const int tid  = threadIdx.x;
    const int lane = tid & 63, wave = tid >> 6;
    const int quad = lane >> 4, l16 = lane & 15;
    const int bh = blockIdx.x;
    const int y  = blockIdx.y;                    // 0..7

    bf16* myU = sU[wave];
    bf16* myP = sP[wave];

    const int srow8 = lane >> 3;
    const int scg   = (lane & 7) ^ srow8;
    const int x8    = l16 & 7;

    // ---- zero U once (band positions pass- and tile-invariant)
    {
        int* p = (int*)myU;
#pragma unroll
        for (int i = 0; i < 13; i++) p[lane + 64 * i] = 0;
    }

    const bf16* Kbh = Kb  + (size_t)bh * 1024 * 64;
    const bf16* Vbh = Vtb + (size_t)bh * 64 * 1024;
    const int b = bh >> 4, h = bh & 15;

    for (int pass = 0; pass < 2; pass++) {
        const int g   = pass ? y : 15 - y;        // heavy strip first
        const int s   = 4 * g + wave;
        const int nkt = g + 1;
        const int B0  = 15 - g;                   // window base block at kt=0

        // ---- Q A-fragments, pre-scaled by 1/8
        bfv8 qf[2];
        {
            const bf16* qp = Qb + ((size_t)bh * 1024 + 16 * s + l16) * 64 + quad * 8;
            qf[0] = *(const bfv8*)qp;
            qf[1] = *(const bfv8*)(qp + 32);
#pragma unroll
            for (int j = 0; j < 8; j++) {
                qf[0][j] = (__bf16)((float)qf[0][j] * 0.125f);
                qf[1][j] = (__bf16)((float)qf[1][j] * 0.125f);
            }
        }

        f4_t zero = {0.f, 0.f, 0.f, 0.f};
        f4_t o_acc[4];
        float m_i[4], l_i[4];
#pragma unroll
        for (int i = 0; i < 4; i++) { o_acc[i] = zero; m_i[i] = -1e30f; l_i[i] = 0.f; }

        // ---- prologue staging (tile 0): K/V, pek blocks {B0,B0+1}, pev {B0..B0+2}
#pragma unroll
        for (int i = 0; i < 2; i++) {
            const int row = 8 * wave + 32 * i + srow8;
            gl2lds16(Kbh + (size_t)row * 64 + scg * 8, &Ks[(8 * wave + 32 * i) * 64]);
            gl2lds16(Vbh + (size_t)row * 1024 + scg * 8, &Vs[(8 * wave + 32 * i) * 64]);
        }
#pragma unroll
        for (int i2 = 0; i2 < 2; i2++) {
            const int slot = (B0 + i2) & 1;
#pragma unroll
            for (int i = 0; i < 2; i++) {
                const int row = 16 * wave + 8 * i + srow8;
                gl2lds16(pekBlk + (size_t)(B0 + i2) * 4096 + row * 64 + scg * 8,
                         &pekR[slot * 4096 + (16 * wave + 8 * i) * 64]);
            }
        }
#pragma unroll
        for (int i2 = 0; i2 < 3; i2++) {
            const int slot = (B0 + i2) % 3;
#pragma unroll
            for (int i = 0; i < 2; i++) {
                const int row = 16 * wave + 8 * i + srow8;
                gl2lds16(pevBlk + (size_t)(B0 + i2) * 4096 + row * 64 + scg * 8,
                         &pevR[slot * 4096 + (16 * wave + 8 * i) * 64]);
            }
        }
        __syncthreads();   // drain for tile-0 staging of this pass

        bfv8 stK[2], stV[2], stPk[2], stPv[2];

        for (int kt = 0; kt < nkt; kt++) {
            const int k0 = kt << 6;
            const int Bb = kt - g + 15;           // window base block, in [0,15]
            const int bm3 = Bb % 3;
            const bool pf = (kt + 1 < nkt);

            if (pf) {   // ---- issue reg loads for tile kt+1 (land during compute)
                const int k0n = (kt + 1) << 6;
                const int bNew = Bb + 2, cNew = Bb + 3;
#pragma unroll
                for (int i = 0; i < 2; i++) {
                    const int row = 8 * wave + 32 * i + srow8;
                    stK[i] = *(const bfv8*)(Kbh + (size_t)(k0n + row) * 64 + scg * 8);
                    stV[i] = *(const bfv8*)(Vbh + (size_t)row * 1024 + k0n + scg * 8);
                }
#pragma unroll
                for (int i = 0; i < 2; i++) {
                    const int row = 16 * wave + 8 * i + srow8;
                    stPk[i] = *(const bfv8*)(pekBlk + (size_t)bNew * 4096 + row * 64 + scg * 8);
                    stPv[i] = *(const bfv8*)(pevBlk + (size_t)cNew * 4096 + row * 64 + scg * 8);
                }
            }

            // ---- S1 = Qs K^T (4 frags), T = Qs Pek^T (5 frags) — all LDS
            f4_t s1[4], tt[5];
#pragma unroll
            for (int i = 0; i < 4; i++) s1[i] = zero;
#pragma unroll
            for (int i = 0; i < 5; i++) tt[i] = zero;
#pragma unroll
            for (int ks = 0; ks < 2; ks++) {
#pragma unroll
                for (int nt = 0; nt < 4; nt++) {
                    bfv8 kf = *(const bfv8*)&Ks[(nt * 16 + l16) * 64 + ((ks * 4 + quad) ^ x8) * 8];
                    s1[nt] = __builtin_amdgcn_mfma_f32_16x16x32_bf16(qf[ks], kf, s1[nt], 0, 0, 0);
                }
#pragma unroll
                for (int nt = 0; nt < 5; nt++) {
                    const int off  = 48 - 16 * wave + 16 * nt;
                    const int slot = (Bb + (off >> 6)) & 1;
                    bfv8 pfr = *(const bfv8*)&pekR[slot * 4096 + ((off & 63) + l16) * 64
                                                  + ((ks * 4 + quad) ^ x8) * 8];
                    tt[nt] = __builtin_amdgcn_mfma_f32_16x16x32_bf16(qf[ks], pfr, tt[nt], 0, 0, 0);
                }
            }

            // ---- skew gather: 5 rotations per row + select; causal mask
            float sc[4][4];
#pragma unroll
            for (int r = 0; r < 4; r++) {
                int qq = quad * 4 + r;
                int t  = l16 + 15 - qq;
                int srcl = quad * 16 + (t & 15);
                bool lo = (t < 16);
                float rot[5];
#pragma unroll
                for (int j = 0; j < 5; j++) rot[j] = __shfl(tt[j][r], srcl, 64);
#pragma unroll
                for (int nt = 0; nt < 4; nt++) {
                    float s2 = lo ? rot[nt] : rot[nt + 1];
                    float v = s1[nt][r] + s2;
                    int kk = nt * 16 + l16;
                    if (k0 + kk > 16 * s + qq) v = -1e30f;
                    sc[nt][r] = v;
                }
            }

            // ---- online softmax with T13 defer-max (THR=8)
            float tmax[4];
            bool keep = true;
#pragma unroll
            for (int r = 0; r < 4; r++) {
                float mt = fmaxf(fmaxf(sc[0][r], sc[1][r]), fmaxf(sc[2][r], sc[3][r]));
                mt = max16(mt);
                tmax[r] = mt;
                keep = keep && (mt - m_i[r] <= 8.0f);
            }
            if (!__all(keep)) {   // rescale path (always taken on first tile)
#pragma unroll
                for (int r = 0; r < 4; r++) {
                    float mnew = fmaxf(m_i[r], tmax[r]);
                    float a = __expf(m_i[r] - mnew);
                    m_i[r] = mnew;
                    l_i[r] *= a;
#pragma unroll
                    for (int nt = 0; nt < 4; nt++) o_acc[nt][r] *= a;
                }
            }
#pragma unroll
            for (int nt = 0; nt < 4; nt++)
#pragma unroll
                for (int r = 0; r < 4; r++)
                    sc[nt][r] = __expf(sc[nt][r] - m_i[r]);
#pragma unroll
            for (int r = 0; r < 4; r++) {
                float rs = sum16(sc[0][r] + sc[1][r] + sc[2][r] + sc[3][r]);
                l_i[r] += rs;
            }

            // ---- scatter P (XOR-swizzled, stride 64) and banded U
#pragma unroll
            for (int nt = 0; nt < 4; nt++)
#pragma unroll
                for (int r = 0; r < 4; r++) {
                    int qq = quad * 4 + r;
                    int kk = nt * 16 + l16;
                    bf16 pb = __float2bfloat16(sc[nt][r]);
                    myP[qq * 64 + (((kk >> 3) ^ (qq & 7)) << 3) + (kk & 7)] = pb;
                    myU[qq * ST + kk - qq + 15] = pb;
                }

            // ---- O += P V ; O += U Pev — all LDS
#pragma unroll
            for (int ks = 0; ks < 2; ks++) {
                bfv8 pa = *(const bfv8*)&myP[l16 * 64 + (((ks * 4 + quad) ^ x8) << 3)];
#pragma unroll
                for (int nt = 0; nt < 4; nt++) {
                    bfv8 vf = *(const bfv8*)&Vs[(nt * 16 + l16) * 64 + ((ks * 4 + quad) ^ x8) * 8];
                    o_acc[nt] = __builtin_amdgcn_mfma_f32_16x16x32_bf16(pa, vf, o_acc[nt], 0, 0, 0);
                }
            }
#pragma unroll
            for (int ks = 0; ks < 3; ks++) {
                bfv8 ua = *(const bfv8*)&myU[l16 * ST + ks * 32 + quad * 8];
                const int off2 = 48 - 16 * wave + 32 * ks + 8 * quad;
                int slot2 = bm3 + (off2 >> 6);
                if (slot2 >= 3) slot2 -= 3;
                const int chunk = (((off2 & 63) >> 3) ^ x8);
#pragma unroll
                for (int nt = 0; nt < 4; nt++) {
                    bfv8 pvf = *(const bfv8*)&pevR[slot2 * 4096 + (nt * 16 + l16) * 64 + chunk * 8];
                    o_acc[nt] = __builtin_amdgcn_mfma_f32_16x16x32_bf16(ua, pvf, o_acc[nt], 0, 0, 0);
                }
            }
            __syncthreads();   // all waves done reading this tile's LDS

            if (pf) {   // ---- write staged regs into LDS (same dests gl2lds used)
                const int Bn = Bb + 1;
                const int slotK = (Bn + 1) & 1, slotV = (Bn + 2) % 3;
#pragma unroll
                for (int i = 0; i < 2; i++) {
                    *(bfv8*)&Ks[(8 * wave + 32 * i) * 64 + lane * 8] = stK[i];
                    *(bfv8*)&Vs[(8 * wave + 32 * i) * 64 + lane * 8] = stV[i];
                }
#pragma unroll
                for (int i = 0; i < 2; i++) {
                    *(bfv8*)&pekR[slotK * 4096 + (16 * wave + 8 * i) * 64 + lane * 8] = stPk[i];
                    *(bfv8*)&pevR[slotV * 4096 + (16 * wave + 8 * i) * 64 + lane * 8] = stPv[i];
                }
            }
            __syncthreads();   // staged writes visible before next tile's compute
        }

        // ---- epilogue for this pass
#pragma unroll
        for (int nt = 0; nt < 4; nt++)
#pragma unroll
            for (int r = 0; r < 4; r++) {
                int q = 16 * s + quad * 4 + r;
                int d = nt * 16 + l16;
                Ob[((size_t)(b * 1024 + q)) * 1024 + h * 64 + d] = __float2bfloat16(o_acc[nt][r] / l_i[r]);
            }
    }
}

// ---------------------------------------------------------------------------
extern "C" void kernel_launch(void* const* d_in, const int* in_sizes, int n_in,
                              void* d_out, int out_size, void* d_ws, size_t ws_size,
                              hipStream_t stream) {
    const float* x   = (const float*)d_in[0];
    const float* Wq  = (const float*)d_in[1];
    const float* Wk  = (const float*)d_in[2];
    const float* Wv  = (const float*)d_in[3];
    const float* Wo  = (const float*)d_in[4];
    const float* pek = (const float*)d_in[5];
    const float* pev = (const float*)d_in[6];

    const size_t MB = 1u << 20;
    char* ws = (char*)d_ws;
    bf16* xb     = (bf16*)(ws + 0);          // 8 MB; dead after QKV gemm -> reused as Ao
    bf16* Wqb    = (bf16*)(ws + 8  * MB);
    bf16* Wkb    = (bf16*)(ws + 10 * MB);
    bf16* Wvb    = (bf16*)(ws + 12 * MB);
    bf16* Wob    = (bf16*)(ws + 14 * MB);
    bf16* Qb     = (bf16*)(ws + 16 * MB);    // Q,K contiguous (z-offset in epilogue)
    bf16* Kb     = (bf16*)(ws + 24 * MB);
    bf16* Vtb    = (bf16*)(ws + 32 * MB);    // V^T written directly by gemm z=2
    bf16* pekBlk = (bf16*)(ws + 48 * MB);            // 17*4096*2 B
    bf16* pevBlk = (bf16*)(ws + 48 * MB + 256*1024); // 18*4096*2 B
    bf16* Ao     = xb;

    prep_all<<<dim3(2066), 256, 0, stream>>>(x, Wq, Wk, Wv, Wo, pek, pev,
                                             xb, Wqb, Wkb, Wvb, Wob, pekBlk, pevBlk);
    gemm_bt4<<<dim3(8, 32, 3), 256, 0, stream>>>(xb, Wqb, Wkb, Wvb, Qb, Vtb, nullptr, 1024, 0);
    attn_k<<<dim3(64, 8), 256, 0, stream>>>(Qb, Kb, Vtb, pekBlk, pevBlk, Ao);
    gemm_bt4<<<dim3(8, 32, 1), 256, 0, stream>>>(Ao, Wob, nullptr, nullptr, nullptr, nullptr, (float*)d_out, 1024, 1);
}